// Round 2
// baseline (1046.324 us; speedup 1.0000x reference)
//
#include <hip/hip_runtime.h>

#define E_CONST 500000
#define N_CONST 100000
#define NT_CONST 15625      // E / 32 edges per tile (exact)
#define GRID_MLP 1536

typedef __attribute__((ext_vector_type(8))) short bf16x8;
typedef __attribute__((ext_vector_type(4))) float f32x4;
typedef __attribute__((ext_vector_type(2))) unsigned u32x2;
typedef __attribute__((ext_vector_type(4))) unsigned u32x4;

// ---------------------------------------------------------------------------
// Prep: swizzle w1 (384x128) and w2 (128x128) fp32 -> bf16 MFMA B-fragments.
// B-frag for tile (kk, nn): lane l holds B[kk*32 + (l>>4)*8 + j][nn*16 + (l&15)],
// stored lane-major: ws[frag*512 + l*8 + j].  w1: frags 0..95, w2: frags 96..127.
// ---------------------------------------------------------------------------
__global__ __launch_bounds__(256) void prep_weights(const float* __restrict__ w1,
                                                    const float* __restrict__ w2,
                                                    short* __restrict__ ws) {
    int idx  = blockIdx.x * 256 + threadIdx.x;   // 0..65535
    int frag = idx >> 9;
    int r    = idx & 511;
    int lane = r >> 3, j = r & 7;
    const float* w;
    int fi;
    if (frag < 96) { w = w1; fi = frag; }
    else           { w = w2; fi = frag - 96; }
    int kk = fi >> 3, nn = fi & 7;
    int k = kk * 32 + (lane >> 4) * 8 + j;
    int n = nn * 16 + (lane & 15);
    unsigned u = __float_as_uint(w[k * 128 + n]);
    u = u + 0x7FFFu + ((u >> 16) & 1u);          // RNE to bf16
    ws[idx] = (short)(u >> 16);
}

// nfeat passthrough -> second tuple output
__global__ __launch_bounds__(256) void copy_nfeat(const float* __restrict__ nfeat,
                                                  float* __restrict__ out) {
    size_t idx = (size_t)(blockIdx.x * 256 + threadIdx.x) * 4;  // exact: 12.8M floats
    *(f32x4*)(out + idx) = *(const f32x4*)(nfeat + idx);
}

__device__ __forceinline__ unsigned pack_bf16_trunc(float lo, float hi) {
    // dst = { hi[31:16], lo[31:16] } in one v_perm_b32
    return __builtin_amdgcn_perm(__float_as_uint(hi), __float_as_uint(lo), 0x07060302u);
}

__device__ __forceinline__ bf16x8 pack8(f32x4 f0, f32x4 f1) {
    u32x4 pk;
    pk.x = pack_bf16_trunc(f0.x, f0.y);
    pk.y = pack_bf16_trunc(f0.z, f0.w);
    pk.z = pack_bf16_trunc(f1.x, f1.y);
    pk.w = pack_bf16_trunc(f1.z, f1.w);
    return __builtin_bit_cast(bf16x8, pk);
}

// Raw barrier: LDS-ordered only. Does NOT drain vmcnt, so register prefetch
// loads stay in flight across tile phases (unlike __syncthreads).
__device__ __forceinline__ void bar_lds() {
    asm volatile("s_waitcnt lgkmcnt(0)" ::: "memory");
    __builtin_amdgcn_s_barrier();
}

// ---------------------------------------------------------------------------
// Pipelined fused kernel. Grid-strided tiles of 32 edges; per tile:
//   P1: GEMM1(t) from As(LDS) + efeat(direct) -> SiLU -> hs[cur]     | barrier
//   P2: pack prefetched gather(t+1) regs -> As; GEMM2(t); LN partials;
//       issue gather(t+2) -> pf regs                                  | barrier
//   P3: LN finalize per-thread; +efeat residual; stores; idx(t+3) -> ni
// Gather latency (scattered nfeat rows) hides under a full tile of compute.
// ---------------------------------------------------------------------------
__global__ __launch_bounds__(256, 2) void edge_mlp(
    const float* __restrict__ efeat, const float* __restrict__ nfeat,
    const int* __restrict__ src, const int* __restrict__ dst,
    const short* __restrict__ wsw,
    const float* __restrict__ b1, const float* __restrict__ b2,
    const float* __restrict__ gamma, const float* __restrict__ beta,
    float* __restrict__ out) {

    __shared__ short As[32 * 264];      // gathered nfeat[src]|nfeat[dst], bf16, +8 pad
    __shared__ short hs[2][32 * 136];   // h tile double buffer, bf16, +8 pad
    __shared__ float psum_s[32 * 4];    // per-row per-wave partial sums
    __shared__ float psq_s[32 * 4];

    const int tid   = threadIdx.x;
    const int lane  = tid & 63;
    const int nw    = tid >> 6;       // wave 0..3
    const int l15   = lane & 15;
    const int quad  = lane >> 4;      // 0..3
    // gather role: 8 lanes cover one 128B chunk of a gathered row
    const int g     = tid >> 3;       // group 0..31
    const int s8    = tid & 7;        // sub-lane
    const int grow  = g >> 2;         // row base 0..7
    const int gpart = g & 3;          // which 128B quarter of the row

    // persistent weight fragments (96 + 32 regs, typically AGPR'd)
    bf16x8 b1f[2][12];
    bf16x8 b2f[2][4];
#pragma unroll
    for (int t = 0; t < 2; ++t) {
        int nn = nw * 2 + t;
#pragma unroll
        for (int kk = 0; kk < 12; ++kk)
            b1f[t][kk] = *(const bf16x8*)(wsw + ((kk * 8 + nn) * 64 + lane) * 8);
#pragma unroll
        for (int kk = 0; kk < 4; ++kk)
            b2f[t][kk] = *(const bf16x8*)(wsw + 49152 + ((kk * 8 + nn) * 64 + lane) * 8);
    }
    const float bb1[2] = { b1[nw * 32 + l15], b1[nw * 32 + 16 + l15] };
    const float bb2[2] = { b2[nw * 32 + l15], b2[nw * 32 + 16 + l15] };
    const float gg[2]  = { gamma[nw * 32 + l15], gamma[nw * 32 + 16 + l15] };
    const float bt[2]  = { beta[nw * 32 + l15],  beta[nw * 32 + 16 + l15] };

    int   ni[8];     // node indices for the NEXT-NEXT tile's gather
    f32x4 pf[8];     // in-flight gather data for the NEXT tile

    int t0 = blockIdx.x;

    // ---- prologue: fill As(t0), start gather(t0+G), load idx(t0+2G) ----
#pragma unroll
    for (int i = 0; i < 8; ++i) {
        int e = t0 * 32 + grow + 8 * (i & 3);
        ni[i] = (i < 4) ? src[e] : dst[e];
    }
#pragma unroll
    for (int i = 0; i < 8; ++i)
        pf[i] = *(const f32x4*)(nfeat + (size_t)ni[i] * 128 + gpart * 32 + s8 * 4);
#pragma unroll
    for (int i = 0; i < 8; ++i) {
        int row = grow + 8 * (i & 3) + ((i >> 2) << 5);  // 0..63 over src|dst halves
        u32x2 w;
        w.x = pack_bf16_trunc(pf[i].x, pf[i].y);
        w.y = pack_bf16_trunc(pf[i].z, pf[i].w);
        *(u32x2*)(As + (row & 31) * 264 + (row >> 5) * 128 + gpart * 32 + s8 * 4) = w;
    }
    if (t0 + GRID_MLP < NT_CONST) {
#pragma unroll
        for (int i = 0; i < 8; ++i) {
            int e = (t0 + GRID_MLP) * 32 + grow + 8 * (i & 3);
            ni[i] = (i < 4) ? src[e] : dst[e];
        }
    }
    bar_lds();
    if (t0 + GRID_MLP < NT_CONST) {
#pragma unroll
        for (int i = 0; i < 8; ++i)
            pf[i] = *(const f32x4*)(nfeat + (size_t)ni[i] * 128 + gpart * 32 + s8 * 4);
    }
    if (t0 + 2 * GRID_MLP < NT_CONST) {
#pragma unroll
        for (int i = 0; i < 8; ++i) {
            int e = (t0 + 2 * GRID_MLP) * 32 + grow + 8 * (i & 3);
            ni[i] = (i < 4) ? src[e] : dst[e];
        }
    }

    int cur = 0;
#pragma unroll 1
    for (int t = t0; t < NT_CONST; t += GRID_MLP) {
        short* hb = &hs[cur][0];

        // ---- P1: GEMM1 + SiLU -> hs[cur] ----
#pragma unroll
        for (int mt = 0; mt < 2; ++mt) {
            size_t e = (size_t)t * 32 + mt * 16 + l15;
            const float* pe = efeat + e * 128 + quad * 8;
            const short* ap = As + (mt * 16 + l15) * 264 + quad * 8;

            f32x4 ef[8];
#pragma unroll
            for (int kk = 0; kk < 4; ++kk) {          // issue efeat loads early
                ef[kk * 2]     = *(const f32x4*)(pe + kk * 32);
                ef[kk * 2 + 1] = *(const f32x4*)(pe + kk * 32 + 4);
            }
            f32x4 acc0 = {0.f, 0.f, 0.f, 0.f}, acc1 = {0.f, 0.f, 0.f, 0.f};
#pragma unroll
            for (int kk = 4; kk < 12; ++kk) {         // LDS slices first (cover efeat)
                bf16x8 a = *(const bf16x8*)(ap + (kk - 4) * 32);
                acc0 = __builtin_amdgcn_mfma_f32_16x16x32_bf16(a, b1f[0][kk], acc0, 0, 0, 0);
                acc1 = __builtin_amdgcn_mfma_f32_16x16x32_bf16(a, b1f[1][kk], acc1, 0, 0, 0);
            }
#pragma unroll
            for (int kk = 0; kk < 4; ++kk) {          // efeat slices
                bf16x8 a = pack8(ef[kk * 2], ef[kk * 2 + 1]);
                acc0 = __builtin_amdgcn_mfma_f32_16x16x32_bf16(a, b1f[0][kk], acc0, 0, 0, 0);
                acc1 = __builtin_amdgcn_mfma_f32_16x16x32_bf16(a, b1f[1][kk], acc1, 0, 0, 0);
            }
#pragma unroll
            for (int tt = 0; tt < 2; ++tt) {
                f32x4 acc = (tt == 0) ? acc0 : acc1;
                int col = nw * 32 + tt * 16 + l15;
#pragma unroll
                for (int i = 0; i < 4; ++i) {
                    float x  = acc[i] + bb1[tt];
                    float sg = __builtin_amdgcn_rcpf(1.0f + __expf(-x));
                    float h  = x * sg;                            // SiLU
                    int row  = mt * 16 + quad * 4 + i;
                    unsigned u = __float_as_uint(h);
                    u = u + 0x7FFFu + ((u >> 16) & 1u);
                    hb[row * 136 + col] = (short)(u >> 16);
                }
            }
        }
        bar_lds();   // B1: As(t) consumed, hs[cur] visible

        // ---- P2: As <- pf (tile t+1); GEMM2; LN partials; issue gather(t+2) ----
        if (t + GRID_MLP < NT_CONST) {
#pragma unroll
            for (int i = 0; i < 8; ++i) {
                int row = grow + 8 * (i & 3) + ((i >> 2) << 5);
                u32x2 w;
                w.x = pack_bf16_trunc(pf[i].x, pf[i].y);
                w.y = pack_bf16_trunc(pf[i].z, pf[i].w);
                *(u32x2*)(As + (row & 31) * 264 + (row >> 5) * 128 + gpart * 32 + s8 * 4) = w;
            }
        }
        if (t + 2 * GRID_MLP < NT_CONST) {
#pragma unroll
            for (int i = 0; i < 8; ++i)
                pf[i] = *(const f32x4*)(nfeat + (size_t)ni[i] * 128 + gpart * 32 + s8 * 4);
        }

        f32x4 y0[2], y1[2];
#pragma unroll
        for (int mt = 0; mt < 2; ++mt) {
            int arow = mt * 16 + l15;
            f32x4 acc0 = {0.f, 0.f, 0.f, 0.f}, acc1 = {0.f, 0.f, 0.f, 0.f};
#pragma unroll
            for (int kk = 0; kk < 4; ++kk) {
                bf16x8 a = *(const bf16x8*)(hb + arow * 136 + kk * 32 + quad * 8);
                acc0 = __builtin_amdgcn_mfma_f32_16x16x32_bf16(a, b2f[0][kk], acc0, 0, 0, 0);
                acc1 = __builtin_amdgcn_mfma_f32_16x16x32_bf16(a, b2f[1][kk], acc1, 0, 0, 0);
            }
            f32x4 bv0 = { bb2[0], bb2[0], bb2[0], bb2[0] };
            f32x4 bv1 = { bb2[1], bb2[1], bb2[1], bb2[1] };
            y0[mt] = acc0 + bv0;
            y1[mt] = acc1 + bv1;
        }

#pragma unroll
        for (int mt = 0; mt < 2; ++mt) {
#pragma unroll
            for (int i = 0; i < 4; ++i) {
                float a0 = y0[mt][i], a1 = y1[mt][i];
                float su = a0 + a1;
                float q  = a0 * a0 + a1 * a1;
                su += __shfl_xor(su, 1);  q += __shfl_xor(q, 1);
                su += __shfl_xor(su, 2);  q += __shfl_xor(q, 2);
                su += __shfl_xor(su, 4);  q += __shfl_xor(q, 4);
                su += __shfl_xor(su, 8);  q += __shfl_xor(q, 8);
                if (l15 == 0) {
                    int row = mt * 16 + quad * 4 + i;
                    psum_s[row * 4 + nw] = su;
                    psq_s [row * 4 + nw] = q;
                }
            }
        }
        bar_lds();   // B2: As(t+1) + partials visible

        // ---- P3: LN finalize (per-thread from partials) + residual + stores ----
#pragma unroll
        for (int mt = 0; mt < 2; ++mt) {
#pragma unroll
            for (int i = 0; i < 4; ++i) {
                int row = mt * 16 + quad * 4 + i;
                f32x4 ps = *(const f32x4*)(psum_s + row * 4);
                f32x4 pq = *(const f32x4*)(psq_s  + row * 4);
                float mu = (ps.x + ps.y + ps.z + ps.w) * (1.0f / 128.0f);
                float m2 = (pq.x + pq.y + pq.z + pq.w) * (1.0f / 128.0f);
                float rs = __builtin_amdgcn_rsqf(m2 - mu * mu + 1e-5f);
                size_t e = (size_t)t * 32 + row;
                int col0 = nw * 32 + l15;
                const float* pef = efeat + e * 128;
                float* po = out + e * 128;
                po[col0]      = (y0[mt][i] - mu) * rs * gg[0] + bt[0] + pef[col0];
                po[col0 + 16] = (y1[mt][i] - mu) * rs * gg[1] + bt[1] + pef[col0 + 16];
            }
        }
        // refill ni for tile t+3 (used for the gather issued in next P2)
        if (t + 3 * GRID_MLP < NT_CONST) {
#pragma unroll
            for (int i = 0; i < 8; ++i) {
                int e = (t + 3 * GRID_MLP) * 32 + grow + 8 * (i & 3);
                ni[i] = (i < 4) ? src[e] : dst[e];
            }
        }
        cur ^= 1;
    }
}

extern "C" void kernel_launch(void* const* d_in, const int* in_sizes, int n_in,
                              void* d_out, int out_size, void* d_ws, size_t ws_size,
                              hipStream_t stream) {
    const float* efeat = (const float*)d_in[0];
    const float* nfeat = (const float*)d_in[1];
    const int*   src   = (const int*)d_in[2];
    const int*   dst   = (const int*)d_in[3];
    const float* w1    = (const float*)d_in[4];
    const float* b1    = (const float*)d_in[5];
    const float* w2    = (const float*)d_in[6];
    const float* b2    = (const float*)d_in[7];
    const float* gamma = (const float*)d_in[8];
    const float* beta  = (const float*)d_in[9];
    float* out = (float*)d_out;
    short* wsw = (short*)d_ws;

    hipLaunchKernelGGL(prep_weights, dim3(256), dim3(256), 0, stream, w1, w2, wsw);
    hipLaunchKernelGGL(copy_nfeat, dim3(12500), dim3(256), 0, stream,
                       nfeat, out + (size_t)E_CONST * 128);
    hipLaunchKernelGGL(edge_mlp, dim3(GRID_MLP), dim3(256), 0, stream,
                       efeat, nfeat, src, dst, wsw, b1, b2, gamma, beta, out);
}